// Round 3
// baseline (12760.283 us; speedup 1.0000x reference)
//
#include <hip/hip_runtime.h>

#define NL 10     // layers
#define NB 64     // batch
#define NT 2048   // time steps
#define NI 14     // input features
#define NH 100    // hidden
#define NS 8      // batch slices
#define BPS 8     // batch rows per slice
#define PADF 108  // fp32 LDS row stride
#define RROW 104  // ring row stride (16B aligned rows)
#define WPAD 116  // bf16 LDS row stride (232B, 8B aligned)
#define NTHR 256
#define FLAGW 16  // unsigned words between flags (64B apart)
#define FLAGBYTES 8192
#define ABORT_IDX (81 * FLAGW)
#define SPIN_CAP (1 << 18)  // ~30-70 ms worst case, then global abort

__device__ __forceinline__ unsigned ld_rlx(const unsigned* p) {
  return __hip_atomic_load(p, __ATOMIC_RELAXED, __HIP_MEMORY_SCOPE_AGENT);
}
__device__ __forceinline__ unsigned ld_acq(const unsigned* p) {
  return __hip_atomic_load(p, __ATOMIC_ACQUIRE, __HIP_MEMORY_SCOPE_AGENT);
}
__device__ __forceinline__ void st_rel(unsigned* p, unsigned v) {
  __hip_atomic_store(p, v, __ATOMIC_RELEASE, __HIP_MEMORY_SCOPE_AGENT);
}
__device__ __forceinline__ unsigned short f2bf(float f) {
  unsigned u = __float_as_uint(f);
  return (unsigned short)((u + 0x7FFFu + ((u >> 16) & 1u)) >> 16);  // RNE
}

// Acquire-poll with watchdog: returns 1 on abort (timeout here or elsewhere).
__device__ __forceinline__ int wait_ge(const unsigned* p, unsigned tgt,
                                       unsigned* abortf) {
  int iters = 0;
  while (ld_acq(p) < tgt) {
    if (++iters > SPIN_CAP) { st_rel(abortf, 1u); return 1; }
    if ((iters & 63) == 0 && ld_rlx(abortf) != 0) return 1;
    __builtin_amdgcn_s_sleep(2);
  }
  return 0;
}

__global__ void zero_flags(unsigned* p) {
  p[blockIdx.x * 256 + threadIdx.x] = 0u;  // 8 blocks x 256 = 8192 B
}

__global__ __launch_bounds__(NTHR)
void rnn_pipe(const float* __restrict__ x, const float* __restrict__ hidden,
              const float* __restrict__ w_ih0, const float* __restrict__ w_ihL,
              const float* __restrict__ w_hh, const float* __restrict__ b_ih,
              const float* __restrict__ b_hh, const float* __restrict__ fc_w,
              const float* __restrict__ fc_b, float* __restrict__ out,
              float* __restrict__ hfin, unsigned* __restrict__ prog,
              float* __restrict__ ring, int D) {
  __shared__ unsigned short WihU[NH * WPAD];  // 23.2 KB bf16
  __shared__ unsigned short WhhU[NH * WPAD];  // 23.2 KB bf16
  __shared__ float hB[BPS][PADF];             // own hidden state (fp32)
  __shared__ float inB[BPS][PADF];            // input activation (fp32)
  __shared__ float biasL[128];
  __shared__ float fcwL[128];
  __shared__ int sAbort;

  const int bid = blockIdx.x;
  const int l = bid / NS;
  const int s = bid - l * NS;
  const int tid = threadIdx.x;
  const int b0 = s * BPS;
  const int kin_real = (l == 0) ? NI : NH;

  // ---- one-time staging: weights (bf16), biases, fc, h0 ----
  const float* wsrc = (l == 0) ? w_ih0 : (w_ihL + (size_t)(l - 1) * NH * NH);
  for (int idx = tid; idx < NH * WPAD; idx += NTHR) {
    int j = idx / WPAD, k = idx - j * WPAD;
    WihU[idx] = (k < kin_real) ? f2bf(wsrc[j * kin_real + k]) : (unsigned short)0;
    WhhU[idx] = (k < NH) ? f2bf(w_hh[(size_t)l * NH * NH + j * NH + k]) : (unsigned short)0;
  }
  for (int idx = tid; idx < 128; idx += NTHR) {
    biasL[idx] = (idx < NH) ? (b_ih[l * NH + idx] + b_hh[l * NH + idx]) : 0.f;
    fcwL[idx] = (idx < NH) ? fc_w[idx] : 0.f;
  }
  for (int idx = tid; idx < BPS * PADF; idx += NTHR) {
    int bb = idx / PADF, k = idx - bb * PADF;
    hB[bb][k] = (k < NH) ? hidden[(size_t)l * NB * NH + (size_t)(b0 + bb) * NH + k] : 0.f;
    inB[bb][k] = 0.f;
  }
  if (tid == 0) sAbort = 0;
  __syncthreads();

  const int b = tid >> 5;   // 0..7 batch row within slice
  const int jg = tid & 31;  // column group
  const int jj0 = jg, jj1 = jg + 32, jj2 = jg + 64, jj3 = jg + 96;
  const int jc3 = (jj3 < NH) ? jj3 : 0;  // clamp invalid, discard later
  const float fcb = fc_b[0];
  const int kin4 = (l == 0) ? 4 : 25;  // float4 iterations over input K

  const unsigned* pin = prog + ((l - 1) * NS + s) * FLAGW;
  const unsigned* pout = prog + ((l + 1) * NS + s) * FLAGW;
  unsigned* pme = prog + (l * NS + s) * FLAGW;
  unsigned* abortf = prog + ABORT_IDX;

  for (int t = 0; t < NT; ++t) {
    // ---- wait for input ready / ring slot free (acquire poll + watchdog) ----
    if (tid == 0) {
      int ab = 0;
      if (l > 0) ab |= wait_ge(pin, (unsigned)(t + 1), abortf);
      if (!ab && l < NL - 1 && t >= D)
        ab |= wait_ge(pout, (unsigned)(t - D + 1), abortf);
      sAbort = ab;
    }
    __syncthreads();
    if (sAbort) return;  // uniform across block: safe

    // ---- stage input tile into LDS ----
    if (l == 0) {
      if (tid < BPS * NI) {
        int r = tid / NI, i = tid - r * NI;
        inB[r][i] = x[(size_t)(b0 + r) * (NT * NI) + (size_t)t * NI + i];
      }
    } else {
      const float4* src4 = (const float4*)(ring +
          (size_t)(((l - 1) * NS + s) * D + (t & (D - 1))) * (BPS * RROW));
      if (tid < BPS * (RROW / 4)) {  // 208 float4s
        int r = tid / 26, c = tid - r * 26;
        *(float4*)&inB[r][c * 4] = src4[tid];
      }
    }
    __syncthreads();

    // ---- FMA core: 4 output columns per thread, K = 100 + Kin ----
    float a0 = biasL[jj0], a1 = biasL[jj1], a2 = biasL[jj2], a3 = biasL[jc3];
    {
      const uint2* r0 = (const uint2*)&WhhU[jj0 * WPAD];
      const uint2* r1 = (const uint2*)&WhhU[jj1 * WPAD];
      const uint2* r2 = (const uint2*)&WhhU[jj2 * WPAD];
      const uint2* r3 = (const uint2*)&WhhU[jc3 * WPAD];
      const float4* ap = (const float4*)&hB[b][0];
#pragma unroll 5
      for (int k4 = 0; k4 < 25; ++k4) {
        float4 a = ap[k4];
        uint2 d;
        d = r0[k4];
        a0 = fmaf(a.x, __uint_as_float(d.x << 16), a0);
        a0 = fmaf(a.y, __uint_as_float(d.x & 0xFFFF0000u), a0);
        a0 = fmaf(a.z, __uint_as_float(d.y << 16), a0);
        a0 = fmaf(a.w, __uint_as_float(d.y & 0xFFFF0000u), a0);
        d = r1[k4];
        a1 = fmaf(a.x, __uint_as_float(d.x << 16), a1);
        a1 = fmaf(a.y, __uint_as_float(d.x & 0xFFFF0000u), a1);
        a1 = fmaf(a.z, __uint_as_float(d.y << 16), a1);
        a1 = fmaf(a.w, __uint_as_float(d.y & 0xFFFF0000u), a1);
        d = r2[k4];
        a2 = fmaf(a.x, __uint_as_float(d.x << 16), a2);
        a2 = fmaf(a.y, __uint_as_float(d.x & 0xFFFF0000u), a2);
        a2 = fmaf(a.z, __uint_as_float(d.y << 16), a2);
        a2 = fmaf(a.w, __uint_as_float(d.y & 0xFFFF0000u), a2);
        d = r3[k4];
        a3 = fmaf(a.x, __uint_as_float(d.x << 16), a3);
        a3 = fmaf(a.y, __uint_as_float(d.x & 0xFFFF0000u), a3);
        a3 = fmaf(a.z, __uint_as_float(d.y << 16), a3);
        a3 = fmaf(a.w, __uint_as_float(d.y & 0xFFFF0000u), a3);
      }
    }
    {
      const uint2* r0 = (const uint2*)&WihU[jj0 * WPAD];
      const uint2* r1 = (const uint2*)&WihU[jj1 * WPAD];
      const uint2* r2 = (const uint2*)&WihU[jj2 * WPAD];
      const uint2* r3 = (const uint2*)&WihU[jc3 * WPAD];
      const float4* ap = (const float4*)&inB[b][0];
#pragma unroll 5
      for (int k4 = 0; k4 < kin4; ++k4) {
        float4 a = ap[k4];
        uint2 d;
        d = r0[k4];
        a0 = fmaf(a.x, __uint_as_float(d.x << 16), a0);
        a0 = fmaf(a.y, __uint_as_float(d.x & 0xFFFF0000u), a0);
        a0 = fmaf(a.z, __uint_as_float(d.y << 16), a0);
        a0 = fmaf(a.w, __uint_as_float(d.y & 0xFFFF0000u), a0);
        d = r1[k4];
        a1 = fmaf(a.x, __uint_as_float(d.x << 16), a1);
        a1 = fmaf(a.y, __uint_as_float(d.x & 0xFFFF0000u), a1);
        a1 = fmaf(a.z, __uint_as_float(d.y << 16), a1);
        a1 = fmaf(a.w, __uint_as_float(d.y & 0xFFFF0000u), a1);
        d = r2[k4];
        a2 = fmaf(a.x, __uint_as_float(d.x << 16), a2);
        a2 = fmaf(a.y, __uint_as_float(d.x & 0xFFFF0000u), a2);
        a2 = fmaf(a.z, __uint_as_float(d.y << 16), a2);
        a2 = fmaf(a.w, __uint_as_float(d.y & 0xFFFF0000u), a2);
        d = r3[k4];
        a3 = fmaf(a.x, __uint_as_float(d.x << 16), a3);
        a3 = fmaf(a.y, __uint_as_float(d.x & 0xFFFF0000u), a3);
        a3 = fmaf(a.z, __uint_as_float(d.y << 16), a3);
        a3 = fmaf(a.w, __uint_as_float(d.y & 0xFFFF0000u), a3);
      }
    }
    __syncthreads();  // FMA readers done before h overwrite

    // ---- epilogue: tanh, update h, emit to ring / h_final ----
    float v0 = tanhf(a0), v1 = tanhf(a1), v2 = tanhf(a2), v3 = 0.f;
    if (jj3 < NH) v3 = tanhf(a3);
    hB[b][jj0] = v0;
    hB[b][jj1] = v1;
    hB[b][jj2] = v2;
    if (jj3 < NH) hB[b][jj3] = v3;
    if (l < NL - 1) {
      float* dst = ring + (size_t)((l * NS + s) * D + (t & (D - 1))) * (BPS * RROW) +
                   (size_t)b * RROW;
      dst[jj0] = v0;
      dst[jj1] = v1;
      dst[jj2] = v2;
      if (jj3 < NH) dst[jj3] = v3;
    }
    if (t == NT - 1) {
      float* hf = hfin + (size_t)l * NB * NH + (size_t)(b0 + b) * NH;
      hf[jj0] = v0;
      hf[jj1] = v1;
      hf[jj2] = v2;
      if (jj3 < NH) hf[jj3] = v3;
    }
    __syncthreads();  // all waves' h/ring stores drained (vmcnt(0)) before flag

    // ---- top layer: fused FC (O=1) ----
    if (l == NL - 1 && tid < 64) {
      int bb = tid >> 3, ks = tid & 7;
      float sum = 0.f;
      for (int k = ks; k < NH; k += 8) sum += hB[bb][k] * fcwL[k];
      sum += __shfl_xor(sum, 1);
      sum += __shfl_xor(sum, 2);
      sum += __shfl_xor(sum, 4);
      if (ks == 0) out[(size_t)(b0 + bb) * NT + t] = sum + fcb;
    }

    // ---- publish progress (release store: L2 writeback then flag) ----
    if (tid == 0) st_rel(pme, (unsigned)(t + 1));
  }
}

extern "C" void kernel_launch(void* const* d_in, const int* in_sizes, int n_in,
                              void* d_out, int out_size, void* d_ws, size_t ws_size,
                              hipStream_t stream) {
  const float* x = (const float*)d_in[0];
  const float* hidden = (const float*)d_in[1];
  const float* w_ih0 = (const float*)d_in[2];
  const float* w_ihL = (const float*)d_in[3];
  const float* w_hh = (const float*)d_in[4];
  const float* b_ih = (const float*)d_in[5];
  const float* b_hh = (const float*)d_in[6];
  const float* fc_w = (const float*)d_in[7];
  const float* fc_b = (const float*)d_in[8];
  float* out = (float*)d_out;
  float* hfin = out + (size_t)NB * NT;  // 131072
  unsigned* prog = (unsigned*)d_ws;
  float* ring = (float*)((char*)d_ws + FLAGBYTES);

  // ring depth: power of two, shrink to fit ws; bail out if even D=1 doesn't fit
  const size_t ring_bytes_per_d = (size_t)(NL - 1) * NS * BPS * RROW * 4;
  if (ws_size < FLAGBYTES + ring_bytes_per_d) return;  // fail safe, no OOB
  int D = 16;
  while (D > 1 && FLAGBYTES + (size_t)D * ring_bytes_per_d > ws_size) D >>= 1;

  zero_flags<<<8, 256, 0, stream>>>(prog);  // capture-safe flag reset each call
  rnn_pipe<<<NL * NS, NTHR, 0, stream>>>(x, hidden, w_ih0, w_ihL, w_hh, b_ih,
                                         b_hh, fc_w, fc_b, out, hfin, prog,
                                         ring, D);
}

// Round 5
// 5237.312 us; speedup vs baseline: 2.4364x; 2.4364x over previous
//
#include <hip/hip_runtime.h>

#define NL 10   // layers
#define NB 64   // batch
#define NT 2048 // time steps
#define NI 14   // input features
#define NH 100  // hidden
#define NS 4    // batch slices
#define BPS 16  // batch rows per slice (= MFMA M)
#define CH 4    // timesteps per published chunk
#define NTC (NT / CH)
#define HSTR 136  // LDS h row stride in ushorts (272B; (rowl+kg)%8 uniform)
#define RC 128    // ring row cols (bf16, zero-padded 100..127)
#define PLANE (CH * BPS * RC)  // ushorts per (hi|lo) plane = 8192
#define RSLOT2 (2 * PLANE)     // ushorts per chunk slot (32 KB)
#define NTHR 256
#define FLAGW 16
#define FLAGBYTES 8192
#define ABORT_IDX (NL * NS * FLAGW)
#define SPIN_CAP (1 << 18)

typedef __attribute__((ext_vector_type(8))) short short8v;  // 8 bf16 = 4 VGPR
typedef __attribute__((ext_vector_type(4))) float f32x4;

__device__ __forceinline__ unsigned ld_rlx(const unsigned* p) {
  return __hip_atomic_load(p, __ATOMIC_RELAXED, __HIP_MEMORY_SCOPE_AGENT);
}
__device__ __forceinline__ unsigned ld_acq(const unsigned* p) {
  return __hip_atomic_load(p, __ATOMIC_ACQUIRE, __HIP_MEMORY_SCOPE_AGENT);
}
__device__ __forceinline__ void st_rel(unsigned* p, unsigned v) {
  __hip_atomic_store(p, v, __ATOMIC_RELEASE, __HIP_MEMORY_SCOPE_AGENT);
}
__device__ __forceinline__ unsigned short f2bf(float f) {
  unsigned u = __float_as_uint(f);
  return (unsigned short)((u + 0x7FFFu + ((u >> 16) & 1u)) >> 16);  // RNE
}
__device__ __forceinline__ float bf2f(unsigned short u) {
  return __uint_as_float((unsigned)u << 16);
}
__device__ __forceinline__ float fast_tanh(float v) {
  float e = __expf(2.f * v);
  return 1.f - 2.f / (e + 1.f);
}

__device__ __forceinline__ int wait_ge(const unsigned* p, unsigned tgt,
                                       unsigned* abortf) {
  int iters = 0;
  while (ld_acq(p) < tgt) {
    if (++iters > SPIN_CAP) { st_rel(abortf, 1u); return 1; }
    if ((iters & 63) == 0 && ld_rlx(abortf) != 0) return 1;
    __builtin_amdgcn_s_sleep(2);
  }
  return 0;
}

__global__ void zero_flags(unsigned* p) {
  p[blockIdx.x * 256 + threadIdx.x] = 0u;
}

__global__ __launch_bounds__(NTHR, 1)
void rnn_mfma(const float* __restrict__ x, const float* __restrict__ hidden,
              const float* __restrict__ w_ih0, const float* __restrict__ w_ihL,
              const float* __restrict__ w_hh, const float* __restrict__ b_ih,
              const float* __restrict__ b_hh, const float* __restrict__ fc_w,
              const float* __restrict__ fc_b, float* __restrict__ out,
              float* __restrict__ hfin, unsigned* __restrict__ prog,
              unsigned short* __restrict__ ring, int D) {
  __shared__ unsigned short hHi[BPS][HSTR];  // h hi-plane, cols >=100 zero
  __shared__ unsigned short hLo[BPS][HSTR];  // h lo-plane (residual)
  __shared__ float fcwL[112];
  __shared__ int sAbort;

  const int bid = blockIdx.x;
  const int l = bid / NS;
  const int s = bid - l * NS;
  const int tid = threadIdx.x;
  const int b0 = s * BPS;
  const int w = tid >> 6;        // wave id 0..3
  const int ln = tid & 63;       // lane in wave
  const int rowl = ln & 15;      // A row / B col / D col index
  const int kg = (ln >> 4) & 3;  // k-group (8 k's per K=32 chunk)

  // ---- init LDS: h0 split hi/lo, fc weights ----
  for (int i = tid; i < BPS * HSTR; i += NTHR) {
    int r = i / HSTR, cc = i - r * HSTR;
    unsigned short hv = 0, lv = 0;
    if (cc < NH) {
      float f = hidden[(size_t)l * NB * NH + (size_t)(b0 + r) * NH + cc];
      hv = f2bf(f);
      lv = f2bf(f - bf2f(hv));
    }
    (&hHi[0][0])[i] = hv;
    (&hLo[0][0])[i] = lv;
  }
  for (int i = tid; i < 112; i += NTHR) fcwL[i] = (i < NH) ? fc_w[i] : 0.f;
  if (tid == 0) sAbort = 0;

  // ---- persistent weight B-fragments in VGPRs (wave w: cols 2w*16, (2w+1)*16) ----
  const int j0 = (w * 2) * 16 + rowl;
  const int j1 = (w * 2 + 1) * 16 + rowl;
  const float* Whh = w_hh + (size_t)l * NH * NH;
  const float* Wih = (l == 0) ? w_ih0 : (w_ihL + (size_t)(l - 1) * NH * NH);
  const int KI = (l == 0) ? NI : NH;

  short8v bhh0[4], bhh1[4], bih0[4], bih1[4];
#pragma unroll
  for (int kc = 0; kc < 4; ++kc) {
    short8v f0 = {}, f1 = {}, g0 = {}, g1 = {};
    const int kb = kc * 32 + kg * 8;
#pragma unroll
    for (int e = 0; e < 8; ++e) {
      const int k = kb + e;
      if (k < NH) {
        if (j0 < NH) f0[e] = (short)f2bf(Whh[j0 * NH + k]);
        if (j1 < NH) f1[e] = (short)f2bf(Whh[j1 * NH + k]);
      }
      if (k < KI) {
        if (j0 < NH) g0[e] = (short)f2bf(Wih[j0 * KI + k]);
        if (j1 < NH) g1[e] = (short)f2bf(Wih[j1 * KI + k]);
      }
    }
    bhh0[kc] = f0; bhh1[kc] = f1; bih0[kc] = g0; bih1[kc] = g1;
  }
  const float bias0 = (j0 < NH) ? b_ih[l * NH + j0] + b_hh[l * NH + j0] : 0.f;
  const float bias1 = (j1 < NH) ? b_ih[l * NH + j1] + b_hh[l * NH + j1] : 0.f;
  const float fcb = fc_b[0];

  const unsigned* pin = prog + ((l > 0 ? (l - 1) * NS + s : 0)) * FLAGW;
  const unsigned* pout = prog + ((l < NL - 1 ? (l + 1) * NS + s : 0)) * FLAGW;
  unsigned* pme = prog + (l * NS + s) * FLAGW;
  unsigned* abortf = prog + ABORT_IDX;

  const unsigned short* rin =
      ring + (size_t)(l > 0 ? (l - 1) * NS + s : 0) * D * RSLOT2;
  unsigned short* rout = ring + (size_t)(l * NS + s) * D * RSLOT2;

  __syncthreads();

  for (int c = 0; c < NTC; ++c) {
    // ---- chunk-level sync ----
    if (tid == 0) {
      int ab = 0;
      if (l > 0) ab |= wait_ge(pin, (unsigned)(c + 1), abortf);
      if (!ab && l < NL - 1 && c >= D)
        ab |= wait_ge(pout, (unsigned)(c - D + 1), abortf);
      sAbort = ab;
    }
    __syncthreads();
    if (sAbort) return;

    // ---- layer-0: stage x hi/lo fragments for the chunk ----
    short8v xh[CH], xl[CH];
    if (l == 0) {
#pragma unroll
      for (int st = 0; st < CH; ++st) {
        short8v hh = {}, ll = {};
        const float* xp =
            x + (size_t)(b0 + rowl) * (NT * NI) + (size_t)(c * CH + st) * NI;
        if (kg < 2) {
#pragma unroll
          for (int e = 0; e < 8; ++e) {
            const int k = kg * 8 + e;
            if (k < NI) {
              float f = xp[k];
              unsigned short hu = f2bf(f);
              hh[e] = (short)hu;
              ll[e] = (short)f2bf(f - bf2f(hu));
            }
          }
        }
        xh[st] = hh; xl[st] = ll;
      }
    }

    const unsigned short* rbc = rin + (size_t)(c % D) * RSLOT2;
    unsigned short* robc = rout + (size_t)(c % D) * RSLOT2;

    // ---- CH recurrent steps ----
#pragma unroll
    for (int st = 0; st < CH; ++st) {
      const int t = c * CH + st;

      // ih fragments (global: ring hi/lo, or x split) — issued early so the
      // hh MFMA chain hides the L2/HBM latency
      short8v ihh[4], ihl[4];
      if (l == 0) {
        ihh[0] = xh[st]; ihl[0] = xl[st];
        ihh[1] = short8v{}; ihh[2] = short8v{}; ihh[3] = short8v{};
        ihl[1] = short8v{}; ihl[2] = short8v{}; ihl[3] = short8v{};
      } else {
        const unsigned short* rbase = rbc + (st * BPS + rowl) * RC + kg * 8;
        ihh[0] = *(const short8v*)(rbase + 0);
        ihh[1] = *(const short8v*)(rbase + 32);
        ihh[2] = *(const short8v*)(rbase + 64);
        ihh[3] = *(const short8v*)(rbase + 96);
        ihl[0] = *(const short8v*)(rbase + PLANE + 0);
        ihl[1] = *(const short8v*)(rbase + PLANE + 32);
        ihl[2] = *(const short8v*)(rbase + PLANE + 64);
        ihl[3] = *(const short8v*)(rbase + PLANE + 96);
      }

      // hh fragments (LDS, hi + lo)
      short8v ahh[4], alo[4];
#pragma unroll
      for (int kc = 0; kc < 4; ++kc) {
        ahh[kc] = *(const short8v*)&hHi[rowl][kc * 32 + kg * 8];
        alo[kc] = *(const short8v*)&hLo[rowl][kc * 32 + kg * 8];
      }

      f32x4 acc0 = {bias0, bias0, bias0, bias0};
      f32x4 acc1 = {bias1, bias1, bias1, bias1};
#pragma unroll
      for (int kc = 0; kc < 4; ++kc) {
        acc0 = __builtin_amdgcn_mfma_f32_16x16x32_bf16(ahh[kc], bhh0[kc], acc0, 0, 0, 0);
        acc1 = __builtin_amdgcn_mfma_f32_16x16x32_bf16(ahh[kc], bhh1[kc], acc1, 0, 0, 0);
        acc0 = __builtin_amdgcn_mfma_f32_16x16x32_bf16(alo[kc], bhh0[kc], acc0, 0, 0, 0);
        acc1 = __builtin_amdgcn_mfma_f32_16x16x32_bf16(alo[kc], bhh1[kc], acc1, 0, 0, 0);
      }
#pragma unroll
      for (int kc = 0; kc < 4; ++kc) {
        acc0 = __builtin_amdgcn_mfma_f32_16x16x32_bf16(ihh[kc], bih0[kc], acc0, 0, 0, 0);
        acc1 = __builtin_amdgcn_mfma_f32_16x16x32_bf16(ihh[kc], bih1[kc], acc1, 0, 0, 0);
        acc0 = __builtin_amdgcn_mfma_f32_16x16x32_bf16(ihl[kc], bih0[kc], acc0, 0, 0, 0);
        acc1 = __builtin_amdgcn_mfma_f32_16x16x32_bf16(ihl[kc], bih1[kc], acc1, 0, 0, 0);
      }

      // tanh + hi/lo split
      unsigned short nh0[4], nl0[4], nh1[4], nl1[4];
#pragma unroll
      for (int r = 0; r < 4; ++r) {
        float v0 = fast_tanh(acc0[r]);
        float v1 = fast_tanh(acc1[r]);
        nh0[r] = f2bf(v0); nl0[r] = f2bf(v0 - bf2f(nh0[r]));
        nh1[r] = f2bf(v1); nl1[r] = f2bf(v1 - bf2f(nh1[r]));
      }

      __syncthreads();  // all waves done reading hHi/hLo for this step

      // D layout (m89): col = lane&15, row = (lane>>4)*4 + reg
#pragma unroll
      for (int r = 0; r < 4; ++r) {
        const int m = kg * 4 + r;
        if (j0 < NH) { hHi[m][j0] = nh0[r]; hLo[m][j0] = nl0[r]; }
        if (j1 < NH) { hHi[m][j1] = nh1[r]; hLo[m][j1] = nl1[r]; }
      }
      __syncthreads();  // h(t) complete in LDS

      if (l < NL - 1) {
        // full-plane ring copy: 256 threads x 8 ushorts covers 16x128 (hi & lo)
        const int rr = tid >> 4;          // 0..15
        const int c8 = (tid & 15) * 8;    // 0..120
        unsigned short* dst = robc + (st * BPS + rr) * RC + c8;
        *(short8v*)dst = *(const short8v*)&hHi[rr][c8];
        *(short8v*)(dst + PLANE) = *(const short8v*)&hLo[rr][c8];
      } else {
        // fused FC (O=1): 16 lanes per batch row, shfl reduce
        const int r = tid >> 4, ks = tid & 15;
        float sum = 0.f;
        for (int k = ks; k < NH; k += 16)
          sum = fmaf(bf2f(hHi[r][k]) + bf2f(hLo[r][k]), fcwL[k], sum);
        sum += __shfl_xor(sum, 1);
        sum += __shfl_xor(sum, 2);
        sum += __shfl_xor(sum, 4);
        sum += __shfl_xor(sum, 8);
        if (ks == 0) out[(size_t)(b0 + r) * NT + t] = sum + fcb;
      }

      if (t == NT - 1) {
        for (int i = tid; i < BPS * NH; i += NTHR) {
          const int r = i / NH, j = i - r * NH;
          hfin[(size_t)l * NB * NH + (size_t)(b0 + r) * NH + j] =
              bf2f(hHi[r][j]) + bf2f(hLo[r][j]);
        }
      }
    }

    __syncthreads();  // per-wave vmcnt(0) drain: ring stores complete
    if (tid == 0) st_rel(pme, (unsigned)(c + 1));
  }
}

extern "C" void kernel_launch(void* const* d_in, const int* in_sizes, int n_in,
                              void* d_out, int out_size, void* d_ws, size_t ws_size,
                              hipStream_t stream) {
  const float* x = (const float*)d_in[0];
  const float* hidden = (const float*)d_in[1];
  const float* w_ih0 = (const float*)d_in[2];
  const float* w_ihL = (const float*)d_in[3];
  const float* w_hh = (const float*)d_in[4];
  const float* b_ih = (const float*)d_in[5];
  const float* b_hh = (const float*)d_in[6];
  const float* fc_w = (const float*)d_in[7];
  const float* fc_b = (const float*)d_in[8];
  float* out = (float*)d_out;
  float* hfin = out + (size_t)NB * NT;  // out [B*T,1] then h_final [L,B,H]
  unsigned* prog = (unsigned*)d_ws;
  unsigned short* ring = (unsigned short*)((char*)d_ws + FLAGBYTES);

  const size_t per_d = (size_t)(NL - 1) * NS * RSLOT2 * 2;  // bytes per depth
  if (ws_size < FLAGBYTES + 2 * per_d) return;  // fail safe, no OOB
  int D = 16;
  while (D > 2 && FLAGBYTES + (size_t)D * per_d > ws_size) D >>= 1;

  zero_flags<<<8, 256, 0, stream>>>(prog);
  rnn_mfma<<<NL * NS, NTHR, 0, stream>>>(x, hidden, w_ih0, w_ihL, w_hh, b_ih,
                                         b_hh, fc_w, fc_b, out, hfin, prog,
                                         ring, D);
}